// Round 1
// baseline (4730.116 us; speedup 1.0000x reference)
//
#include <hip/hip_runtime.h>
#include <math.h>

#define CIN   192
#define C3    576
#define HWSZ  65536   // 256*256
#define NHEADS 6

// ---------------------------------------------------------------------------
// K1/K3: fp32 tiled GEMM for 1x1 conv.
// Y[b, ot.., pt..] = sum_c W[o, c] * X[b, c, p]  (+ optional bias)
// K fixed at 192. M = gridDim.y * 64. Block 256 threads, 64x64 tile, 4x4/thread.
// ---------------------------------------------------------------------------
__global__ __launch_bounds__(256) void conv1x1_gemm(
    const float* __restrict__ X, const float* __restrict__ Wm,
    const float* __restrict__ bias, float* __restrict__ Y, int hasBias) {
  __shared__ float As[16][68];
  __shared__ float Bs[16][68];
  const int pt = blockIdx.x * 64;
  const int ot = blockIdx.y * 64;
  const int b  = blockIdx.z;
  const int Mout = gridDim.y * 64;
  const float* Xb = X + (size_t)b * CIN * HWSZ;
  float* Yb = Y + (size_t)b * (size_t)Mout * HWSZ;
  const int tid = threadIdx.x;
  const int tx = tid & 15, ty = tid >> 4;
  const int oA = tid >> 2;          // 0..63
  const int kA = (tid & 3) * 4;     // 0,4,8,12
  const int kB = tid >> 4;          // 0..15
  const int pB = (tid & 15) * 4;    // 0..60
  float acc[4][4];
#pragma unroll
  for (int i = 0; i < 4; ++i)
#pragma unroll
    for (int j = 0; j < 4; ++j) acc[i][j] = 0.f;

  for (int k0 = 0; k0 < CIN; k0 += 16) {
    float4 av = *(const float4*)(Wm + (size_t)(ot + oA) * CIN + k0 + kA);
    As[kA + 0][oA] = av.x;
    As[kA + 1][oA] = av.y;
    As[kA + 2][oA] = av.z;
    As[kA + 3][oA] = av.w;
    *(float4*)&Bs[kB][pB] =
        *(const float4*)(Xb + (size_t)(k0 + kB) * HWSZ + pt + pB);
    __syncthreads();
#pragma unroll
    for (int k = 0; k < 16; ++k) {
      const float4 a4 = *(const float4*)&As[k][ty * 4];
      const float4 b4 = *(const float4*)&Bs[k][tx * 4];
      const float avr[4] = {a4.x, a4.y, a4.z, a4.w};
      const float bvr[4] = {b4.x, b4.y, b4.z, b4.w};
#pragma unroll
      for (int i = 0; i < 4; ++i)
#pragma unroll
        for (int j = 0; j < 4; ++j) acc[i][j] += avr[i] * bvr[j];
    }
    __syncthreads();
  }
#pragma unroll
  for (int i = 0; i < 4; ++i) {
    const int o = ot + ty * 4 + i;
    const float bv = hasBias ? bias[o] : 0.f;
    float4 r;
    r.x = acc[i][0] + bv;
    r.y = acc[i][1] + bv;
    r.z = acc[i][2] + bv;
    r.w = acc[i][3] + bv;
    *(float4*)(Yb + (size_t)o * HWSZ + pt + tx * 4) = r;
  }
}

// ---------------------------------------------------------------------------
// K2: per-(window, head) block. Fuses depthwise 3x3 conv (halo in LDS),
// l2norm, channel attention (32x32 over 64 tokens), softmax, attn@v,
// GELU(v @ mlp_w^T + b) gate, multiply, write y in (B,192,256,256) layout.
// Block 256 threads. Grid (6 heads, 1024 windows, 2 batch).
// ---------------------------------------------------------------------------
__global__ __launch_bounds__(256) void attn_window(
    const float* __restrict__ qkv, const float* __restrict__ wdw,
    const float* __restrict__ temp, const float* __restrict__ mlpw,
    const float* __restrict__ mlpb, float* __restrict__ Y) {
  __shared__ float tile[32][100];   // one z-group halo tile (32ch x 10 x 10)
  __shared__ float dwv[96][64];     // q(0:32) k(32:64) v(64:96) x 64 tokens
  __shared__ float mwv[4096];       // mlp_w 64x64
  __shared__ float attnS[32][33];
  __shared__ float scl[64];
  const int head = blockIdx.x;
  const int win  = blockIdx.y;
  const int b    = blockIdx.z;
  const int h1 = win >> 5, w1 = win & 31;
  const int tid = threadIdx.x;

  // stage mlp weights (first used after several barriers)
  {
    const float4* src = (const float4*)mlpw;
    float4* dst = (float4*)mwv;
#pragma unroll
    for (int i = 0; i < 4; ++i) dst[tid + 256 * i] = src[tid + 256 * i];
  }

  const int row0 = h1 * 8 - 1, col0 = w1 * 8 - 1;
  for (int g = 0; g < 3; ++g) {
    __syncthreads();  // protect tile[] reuse across groups
    const size_t cbase = (size_t)b * C3 + g * 192 + head * 32;
    for (int idx = tid; idx < 3200; idx += 256) {
      const int ch = idx / 100, rem = idx % 100;
      const int yy = rem / 10, xx = rem % 10;
      const int gy = row0 + yy, gx = col0 + xx;
      float v = 0.f;
      if ((unsigned)gy < 256u && (unsigned)gx < 256u)
        v = qkv[((cbase + ch) * 256 + gy) * 256 + gx];
      tile[ch][rem] = v;
    }
    __syncthreads();
    {  // depthwise 3x3: thread -> (channel, image row)
      const int ch = tid >> 3, iy = tid & 7;
      const float* w9 = wdw + (size_t)(g * 192 + head * 32 + ch) * 9;
      float w[9];
#pragma unroll
      for (int i = 0; i < 9; ++i) w[i] = w9[i];
      float r[3][10];
#pragma unroll
      for (int ry = 0; ry < 3; ++ry)
#pragma unroll
        for (int xx = 0; xx < 10; ++xx)
          r[ry][xx] = tile[ch][(iy + ry) * 10 + xx];
#pragma unroll
      for (int ix = 0; ix < 8; ++ix) {
        const float s = r[0][ix] * w[0] + r[0][ix + 1] * w[1] + r[0][ix + 2] * w[2]
                      + r[1][ix] * w[3] + r[1][ix + 1] * w[4] + r[1][ix + 2] * w[5]
                      + r[2][ix] * w[6] + r[2][ix + 1] * w[7] + r[2][ix + 2] * w[8];
        dwv[g * 32 + ch][iy * 8 + ix] = s;
      }
    }
  }
  __syncthreads();

  // l2norm scales for q rows (0..31) and k rows (32..63)
  if (tid < 64) {
    float ss = 0.f;
#pragma unroll
    for (int x = 0; x < 64; ++x) {
      const float v = dwv[tid][x];
      ss += v * v;
    }
    scl[tid] = 1.f / fmaxf(sqrtf(ss), 1e-12f);
  }
  __syncthreads();

  // attn logits: thread -> (c, 4 d's)
  const float tmpr = temp[head];
  {
    const int c = tid >> 3, d0 = (tid & 7) * 4;
    float s[4] = {0.f, 0.f, 0.f, 0.f};
    for (int x = 0; x < 64; x += 4) {
      const float4 qv = *(const float4*)&dwv[c][x];
#pragma unroll
      for (int j = 0; j < 4; ++j) {
        const float4 kv = *(const float4*)&dwv[32 + d0 + j][x];
        s[j] += qv.x * kv.x + qv.y * kv.y + qv.z * kv.z + qv.w * kv.w;
      }
    }
    const float qs = scl[c];
#pragma unroll
    for (int j = 0; j < 4; ++j)
      attnS[c][d0 + j] = s[j] * qs * scl[32 + d0 + j] * tmpr;
  }
  __syncthreads();

  // softmax per row
  if (tid < 32) {
    float m = -1e30f;
    for (int d = 0; d < 32; ++d) m = fmaxf(m, attnS[tid][d]);
    float sum = 0.f;
    for (int d = 0; d < 32; ++d) {
      const float e = expf(attnS[tid][d] - m);
      attnS[tid][d] = e;
      sum += e;
    }
    const float inv = 1.f / sum;
    for (int d = 0; d < 32; ++d) attnS[tid][d] *= inv;
  }
  __syncthreads();

  // out = attn @ v ; gate = GELU(v @ mlp^T + b) ; y = out * gate
  {
    const int c = tid >> 3, iy = tid & 7, p0 = iy * 8;
    float ov[8];
#pragma unroll
    for (int j = 0; j < 8; ++j) ov[j] = 0.f;
    for (int d = 0; d < 32; ++d) {
      const float a = attnS[c][d];
      const float4 v0 = *(const float4*)&dwv[64 + d][p0];
      const float4 v1 = *(const float4*)&dwv[64 + d][p0 + 4];
      ov[0] += a * v0.x; ov[1] += a * v0.y; ov[2] += a * v0.z; ov[3] += a * v0.w;
      ov[4] += a * v1.x; ov[5] += a * v1.y; ov[6] += a * v1.z; ov[7] += a * v1.w;
    }
    float gt[8];
#pragma unroll
    for (int j = 0; j < 8; ++j) gt[j] = mlpb[p0 + j];
    for (int x = 0; x < 64; x += 4) {
      const float4 vv = *(const float4*)&dwv[64 + c][x];
#pragma unroll
      for (int j = 0; j < 8; ++j) {
        const float4 mv = *(const float4*)&mwv[(p0 + j) * 64 + x];
        gt[j] += vv.x * mv.x + vv.y * mv.y + vv.z * mv.z + vv.w * mv.w;
      }
    }
    float* yp = Y + (((size_t)b * 192 + head * 32 + c) * 256 + (h1 * 8 + iy)) * 256
                + w1 * 8;
#pragma unroll
    for (int j = 0; j < 8; ++j) {
      const float g = gt[j];
      const float gelu = 0.5f * g * (1.f + erff(g * 0.70710678118654752f));
      yp[j] = ov[j] * gelu;
    }
  }
}

extern "C" void kernel_launch(void* const* d_in, const int* in_sizes, int n_in,
                              void* d_out, int out_size, void* d_ws, size_t ws_size,
                              hipStream_t stream) {
  const float* x           = (const float*)d_in[0];
  const float* w_qkv       = (const float*)d_in[1];
  const float* w_dw        = (const float*)d_in[2];
  const float* temperature = (const float*)d_in[3];
  const float* mlp_w       = (const float*)d_in[4];
  const float* mlp_b       = (const float*)d_in[5];
  const float* proj_w      = (const float*)d_in[6];
  const float* proj_b      = (const float*)d_in[7];
  float* out = (float*)d_out;

  float* ws0 = (float*)d_ws;                       // qkv: 2*576*65536 fp32 = 302 MB
  float* ws1 = ws0 + (size_t)2 * C3 * HWSZ;        // y:   2*192*65536 fp32 = 100 MB

  // 1) qkv = W_qkv . x   (M=576)
  conv1x1_gemm<<<dim3(1024, 9, 2), 256, 0, stream>>>(x, w_qkv, nullptr, ws0, 0);
  // 2) fused dwconv + windowed channel attention + mlp gate
  attn_window<<<dim3(NHEADS, 1024, 2), 256, 0, stream>>>(ws0, w_dw, temperature,
                                                         mlp_w, mlp_b, ws1);
  // 3) out = P . y + b    (M=192)
  conv1x1_gemm<<<dim3(1024, 3, 2), 256, 0, stream>>>(ws1, proj_w, proj_b, out, 1);
}

// Round 2
// 2007.244 us; speedup vs baseline: 2.3565x; 2.3565x over previous
//
#include <hip/hip_runtime.h>
#include <math.h>

#define CIN   192
#define C3    576
#define HWSZ  65536   // 256*256

// ---------------------------------------------------------------------------
// K1: fp32 tiled GEMM for qkv 1x1 conv (unchanged from round 0).
// ---------------------------------------------------------------------------
__global__ __launch_bounds__(256) void conv1x1_gemm(
    const float* __restrict__ X, const float* __restrict__ Wm,
    float* __restrict__ Y) {
  __shared__ float As[16][68];
  __shared__ float Bs[16][68];
  const int pt = blockIdx.x * 64;
  const int ot = blockIdx.y * 64;
  const int b  = blockIdx.z;
  const int Mout = gridDim.y * 64;
  const float* Xb = X + (size_t)b * CIN * HWSZ;
  float* Yb = Y + (size_t)b * (size_t)Mout * HWSZ;
  const int tid = threadIdx.x;
  const int tx = tid & 15, ty = tid >> 4;
  const int oA = tid >> 2;
  const int kA = (tid & 3) * 4;
  const int kB = tid >> 4;
  const int pB = (tid & 15) * 4;
  float acc[4][4];
#pragma unroll
  for (int i = 0; i < 4; ++i)
#pragma unroll
    for (int j = 0; j < 4; ++j) acc[i][j] = 0.f;

  for (int k0 = 0; k0 < CIN; k0 += 16) {
    float4 av = *(const float4*)(Wm + (size_t)(ot + oA) * CIN + k0 + kA);
    As[kA + 0][oA] = av.x;
    As[kA + 1][oA] = av.y;
    As[kA + 2][oA] = av.z;
    As[kA + 3][oA] = av.w;
    *(float4*)&Bs[kB][pB] =
        *(const float4*)(Xb + (size_t)(k0 + kB) * HWSZ + pt + pB);
    __syncthreads();
#pragma unroll
    for (int k = 0; k < 16; ++k) {
      const float4 a4 = *(const float4*)&As[k][ty * 4];
      const float4 b4 = *(const float4*)&Bs[k][tx * 4];
      const float avr[4] = {a4.x, a4.y, a4.z, a4.w};
      const float bvr[4] = {b4.x, b4.y, b4.z, b4.w};
#pragma unroll
      for (int i = 0; i < 4; ++i)
#pragma unroll
        for (int j = 0; j < 4; ++j) acc[i][j] += avr[i] * bvr[j];
    }
    __syncthreads();
  }
#pragma unroll
  for (int i = 0; i < 4; ++i) {
    const int o = ot + ty * 4 + i;
    float4 r;
    r.x = acc[i][0]; r.y = acc[i][1]; r.z = acc[i][2]; r.w = acc[i][3];
    *(float4*)(Yb + (size_t)o * HWSZ + pt + tx * 4) = r;
  }
}

// ---------------------------------------------------------------------------
// K2: fused dwconv3x3 + windowed channel attention + mlp gate.
// One block per (b, win, head). Writes yw in windowed layout:
//   yw[((b*1024+win)*192 + head*32 + c)*64 + t]   (contiguous 8 KB per block)
// LDS: token-major dwv (stride 97 -> conflict-free), mlp at stride 65,
// halo tile aliased with mlp buffer. XCD swizzle via bid&7.
// ---------------------------------------------------------------------------
__global__ __launch_bounds__(256, 3) void attn_fused(
    const float* __restrict__ qkv, const float* __restrict__ wdw,
    const float* __restrict__ temp, const float* __restrict__ mlpw,
    const float* __restrict__ mlpb, float* __restrict__ yw) {
  __shared__ float smA[4160];      // phase1: halo tile 32x101; phase5: mlp 64x65
  __shared__ float dwv[64 * 97];   // [token][gc]  gc: q 0..31, k 32..63, v 64..95
  __shared__ float attnS[32 * 33];
  __shared__ float scl[64];

  const int bid = blockIdx.x;           // 0..12287
  const int b   = bid / 6144;
  const int rr  = bid % 6144;
  const int xcd = rr & 7;
  const int s   = rr >> 3;              // 0..767
  const int head = s % 6;
  const int wloc = s / 6;               // 0..127
  const int win  = xcd * 128 + wloc;    // contiguous 128-window band per XCD
  const int h1 = win >> 5, w1 = win & 31;
  const int tid = threadIdx.x;
  const int ch = tid >> 3;              // 0..31
  const int iy = tid & 7;               // 0..7

  const int row0 = h1 * 8 - 1, col0 = w1 * 8 - 1;
  for (int g = 0; g < 3; ++g) {
    __syncthreads();
    const size_t cbase = (size_t)b * C3 + g * 192 + head * 32;
    for (int idx = tid; idx < 3200; idx += 256) {
      const int c = idx / 100, rem = idx - c * 100;
      const int yy = rem / 10, xx = rem - yy * 10;
      const int gy = row0 + yy, gx = col0 + xx;
      float v = 0.f;
      if ((unsigned)gy < 256u && (unsigned)gx < 256u)
        v = qkv[((cbase + c) * 256 + gy) * 256 + gx];
      smA[c * 101 + rem] = v;
    }
    __syncthreads();
    const float* w9 = wdw + (size_t)(g * 192 + head * 32 + ch) * 9;
    const float w0 = w9[0], w1_ = w9[1], w2 = w9[2];
    const float w3 = w9[3], w4 = w9[4], w5 = w9[5];
    const float w6 = w9[6], w7 = w9[7], w8 = w9[8];
    const int gc = g * 32 + ch;
    const float* t0 = &smA[ch * 101 + iy * 10];
#pragma unroll
    for (int ix = 0; ix < 8; ++ix) {
      const float sv = t0[ix] * w0 + t0[ix + 1] * w1_ + t0[ix + 2] * w2
                     + t0[10 + ix] * w3 + t0[11 + ix] * w4 + t0[12 + ix] * w5
                     + t0[20 + ix] * w6 + t0[21 + ix] * w7 + t0[22 + ix] * w8;
      dwv[(iy * 8 + ix) * 97 + gc] = sv;
    }
  }
  __syncthreads();

  // stage mlp weights (aliases halo tile) + l2norm scales
  for (int e = tid; e < 4096; e += 256)
    smA[(e >> 6) * 65 + (e & 63)] = mlpw[e];
  if (tid < 64) {
    float ss = 0.f;
    for (int t = 0; t < 64; ++t) {
      const float v = dwv[t * 97 + tid];
      ss += v * v;
    }
    scl[tid] = 1.f / fmaxf(sqrtf(ss), 1e-12f);
  }
  __syncthreads();

  // logits + softmax (width-8 shuffle reductions; lane group = one q-row)
  {
    const int c = tid >> 3, m = tid & 7;
    float sa[4] = {0.f, 0.f, 0.f, 0.f};
    for (int t = 0; t < 64; ++t) {
      const float qv = dwv[t * 97 + c];
#pragma unroll
      for (int j = 0; j < 4; ++j) sa[j] += qv * dwv[t * 97 + 32 + m * 4 + j];
    }
    const float qs = scl[c] * temp[head];
#pragma unroll
    for (int j = 0; j < 4; ++j) sa[j] *= qs * scl[32 + m * 4 + j];
    float mx = fmaxf(fmaxf(sa[0], sa[1]), fmaxf(sa[2], sa[3]));
    for (int off = 1; off < 8; off <<= 1) mx = fmaxf(mx, __shfl_xor(mx, off, 8));
    float sum = 0.f;
#pragma unroll
    for (int j = 0; j < 4; ++j) {
      sa[j] = expf(sa[j] - mx);
      sum += sa[j];
    }
    for (int off = 1; off < 8; off <<= 1) sum += __shfl_xor(sum, off, 8);
    const float inv = 1.f / sum;
#pragma unroll
    for (int j = 0; j < 4; ++j) attnS[c * 33 + m * 4 + j] = sa[j] * inv;
  }
  __syncthreads();

  // out = attn@v ; gate = GELU(v@mlp^T+b) ; y = out*gate -> windowed write
  {
    const int c = ch;
    float ov[8] = {0.f, 0.f, 0.f, 0.f, 0.f, 0.f, 0.f, 0.f};
    const int tb = iy * 8 * 97 + 64;
    for (int d = 0; d < 32; ++d) {
      const float a = attnS[c * 33 + d];
#pragma unroll
      for (int j = 0; j < 8; ++j) ov[j] += a * dwv[tb + j * 97 + d];
    }
    float gt[8];
#pragma unroll
    for (int j = 0; j < 8; ++j) gt[j] = mlpb[iy * 8 + j];
    for (int x = 0; x < 64; ++x) {
      const float vv = dwv[x * 97 + 64 + c];
#pragma unroll
      for (int j = 0; j < 8; ++j) gt[j] += vv * smA[(iy * 8 + j) * 65 + x];
    }
    float res[8];
#pragma unroll
    for (int j = 0; j < 8; ++j) {
      const float gg = gt[j];
      res[j] = ov[j] * (0.5f * gg * (1.f + erff(gg * 0.70710678118654752f)));
    }
    float* dst = yw + (((size_t)(b * 1024 + win) * 192 + head * 32 + c) * 64
                       + iy * 8);
    *(float4*)dst       = make_float4(res[0], res[1], res[2], res[3]);
    *(float4*)(dst + 4) = make_float4(res[4], res[5], res[6], res[7]);
  }
}

// ---------------------------------------------------------------------------
// K3: proj GEMM reading windowed yw, writing spatial out (+bias).
// p-tile = 4 horizontally adjacent windows (256 tokens); o-tile = 64.
// ---------------------------------------------------------------------------
__global__ __launch_bounds__(256) void proj_gemm(
    const float* __restrict__ yw, const float* __restrict__ Wm,
    const float* __restrict__ bias, float* __restrict__ out) {
  __shared__ float As[16][68];
  __shared__ float Bs[16][256];
  const int ptile = blockIdx.x;         // 0..255
  const int ot = blockIdx.y * 64;
  const int b  = blockIdx.z;
  const int h1 = ptile >> 3, w4 = ptile & 7;
  const int win0 = h1 * 32 + w4 * 4;
  const int tid = threadIdx.x;
  const int tx = tid & 15, ty = tid >> 4;
  const int oA = tid >> 2, kA = (tid & 3) * 4;
  float acc[4][16];
#pragma unroll
  for (int i = 0; i < 4; ++i)
#pragma unroll
    for (int j = 0; j < 16; ++j) acc[i][j] = 0.f;

  const float* ywb = yw + (size_t)(b * 1024 + win0) * 192 * 64;
  for (int k0 = 0; k0 < 192; k0 += 16) {
    float4 av = *(const float4*)(Wm + (size_t)(ot + oA) * 192 + k0 + kA);
    As[kA + 0][oA] = av.x;
    As[kA + 1][oA] = av.y;
    As[kA + 2][oA] = av.z;
    As[kA + 3][oA] = av.w;
#pragma unroll
    for (int i = 0; i < 4; ++i) {
      const int f4 = tid + 256 * i;
      const int k = f4 >> 6, p4 = f4 & 63;
      const int wv = p4 >> 4, tt = (p4 & 15) * 4;
      *(float4*)&Bs[k][p4 * 4] =
          *(const float4*)(ywb + ((size_t)wv * 192 + k0 + k) * 64 + tt);
    }
    __syncthreads();
#pragma unroll
    for (int k = 0; k < 16; ++k) {
      const float a0 = As[k][ty * 4 + 0];
      const float a1 = As[k][ty * 4 + 1];
      const float a2 = As[k][ty * 4 + 2];
      const float a3 = As[k][ty * 4 + 3];
#pragma unroll
      for (int j = 0; j < 16; ++j) {
        const float bv = Bs[k][tx + 16 * j];
        acc[0][j] += a0 * bv;
        acc[1][j] += a1 * bv;
        acc[2][j] += a2 * bv;
        acc[3][j] += a3 * bv;
      }
    }
    __syncthreads();
  }
  const int colbase = w4 * 32;
#pragma unroll
  for (int i = 0; i < 4; ++i) {
    const int o = ot + ty * 4 + i;
    const float bv = bias[o];
    float* ob = out + ((size_t)(b * 192 + o) * 256 + h1 * 8) * 256 + colbase;
#pragma unroll
    for (int j = 0; j < 16; ++j) {
      const int p = tx + 16 * j;
      const int wv = p >> 6;
      const int t = p & 63;
      ob[(t >> 3) * 256 + wv * 8 + (t & 7)] = acc[i][j] + bv;
    }
  }
}

extern "C" void kernel_launch(void* const* d_in, const int* in_sizes, int n_in,
                              void* d_out, int out_size, void* d_ws, size_t ws_size,
                              hipStream_t stream) {
  const float* x           = (const float*)d_in[0];
  const float* w_qkv       = (const float*)d_in[1];
  const float* w_dw        = (const float*)d_in[2];
  const float* temperature = (const float*)d_in[3];
  const float* mlp_w       = (const float*)d_in[4];
  const float* mlp_b       = (const float*)d_in[5];
  const float* proj_w      = (const float*)d_in[6];
  const float* proj_b      = (const float*)d_in[7];
  float* out = (float*)d_out;

  float* ws0 = (float*)d_ws;                       // qkv spatial: 302 MB
  float* yw  = ws0 + (size_t)2 * C3 * HWSZ;        // windowed y: 100 MB

  conv1x1_gemm<<<dim3(1024, 9, 2), 256, 0, stream>>>(x, w_qkv, ws0);
  attn_fused<<<dim3(12288), 256, 0, stream>>>(ws0, w_dw, temperature,
                                              mlp_w, mlp_b, yw);
  proj_gemm<<<dim3(256, 3, 2), 256, 0, stream>>>(yw, proj_w, proj_b, out);
}

// Round 3
// 1967.410 us; speedup vs baseline: 2.4042x; 1.0202x over previous
//
#include <hip/hip_runtime.h>
#include <math.h>

#define CIN   192
#define C3    576
#define HWSZ  65536   // 256*256

// ---------------------------------------------------------------------------
// K1: fp32 tiled GEMM for qkv 1x1 conv (spatial output).
// ---------------------------------------------------------------------------
__global__ __launch_bounds__(256) void conv1x1_gemm(
    const float* __restrict__ X, const float* __restrict__ Wm,
    float* __restrict__ Y) {
  __shared__ float As[16][68];
  __shared__ float Bs[16][68];
  const int pt = blockIdx.x * 64;
  const int ot = blockIdx.y * 64;
  const int b  = blockIdx.z;
  const int Mout = gridDim.y * 64;
  const float* Xb = X + (size_t)b * CIN * HWSZ;
  float* Yb = Y + (size_t)b * (size_t)Mout * HWSZ;
  const int tid = threadIdx.x;
  const int tx = tid & 15, ty = tid >> 4;
  const int oA = tid >> 2;
  const int kA = (tid & 3) * 4;
  const int kB = tid >> 4;
  const int pB = (tid & 15) * 4;
  float acc[4][4];
#pragma unroll
  for (int i = 0; i < 4; ++i)
#pragma unroll
    for (int j = 0; j < 4; ++j) acc[i][j] = 0.f;

  for (int k0 = 0; k0 < CIN; k0 += 16) {
    float4 av = *(const float4*)(Wm + (size_t)(ot + oA) * CIN + k0 + kA);
    As[kA + 0][oA] = av.x;
    As[kA + 1][oA] = av.y;
    As[kA + 2][oA] = av.z;
    As[kA + 3][oA] = av.w;
    *(float4*)&Bs[kB][pB] =
        *(const float4*)(Xb + (size_t)(k0 + kB) * HWSZ + pt + pB);
    __syncthreads();
#pragma unroll
    for (int k = 0; k < 16; ++k) {
      const float4 a4 = *(const float4*)&As[k][ty * 4];
      const float4 b4 = *(const float4*)&Bs[k][tx * 4];
      const float avr[4] = {a4.x, a4.y, a4.z, a4.w};
      const float bvr[4] = {b4.x, b4.y, b4.z, b4.w};
#pragma unroll
      for (int i = 0; i < 4; ++i)
#pragma unroll
        for (int j = 0; j < 4; ++j) acc[i][j] += avr[i] * bvr[j];
    }
    __syncthreads();
  }
#pragma unroll
  for (int i = 0; i < 4; ++i) {
    const int o = ot + ty * 4 + i;
    float4 r;
    r.x = acc[i][0]; r.y = acc[i][1]; r.z = acc[i][2]; r.w = acc[i][3];
    *(float4*)(Yb + (size_t)o * HWSZ + pt + tx * 4) = r;
  }
}

// ---------------------------------------------------------------------------
// K2a: depthwise 3x3 conv. One block per (channel gc, window-row h1, batch).
// Reads spatial qkv rows 8*h1-1 .. 8*h1+8 (full 256-col contiguous rows),
// writes windowed layout: Bw[((b*1024+win)*576 + gc)*64 + t].
// ---------------------------------------------------------------------------
__global__ __launch_bounds__(256) void dwconv_win(
    const float* __restrict__ qkv, const float* __restrict__ wdw,
    float* __restrict__ Bw) {
  __shared__ float t[10][260];   // padded cols: spatial col c -> t[.][c+1]
  const int gc = blockIdx.x;     // 0..575
  const int h1 = blockIdx.y;     // 0..31
  const int b  = blockIdx.z;
  const int tid = threadIdx.x;
  const int r0 = h1 * 8 - 1;
  const float* src = qkv + ((size_t)b * C3 + gc) * HWSZ;

  for (int idx = tid; idx < 640; idx += 256) {
    const int row = idx >> 6, cv = idx & 63;
    const int gr = r0 + row;
    float4 v = make_float4(0.f, 0.f, 0.f, 0.f);
    if ((unsigned)gr < 256u) v = *(const float4*)(src + gr * 256 + cv * 4);
    *(float4*)&t[row][1 + cv * 4] = v;
  }
  if (tid < 10) { t[tid][0] = 0.f; t[tid][257] = 0.f; }
  __syncthreads();

  const float* w9 = wdw + (size_t)gc * 9;
  const float w0 = w9[0], w1 = w9[1], w2 = w9[2];
  const float w3 = w9[3], w4 = w9[4], w5 = w9[5];
  const float w6 = w9[6], w7 = w9[7], w8 = w9[8];

  const int c = tid;                  // spatial col 0..255
  const int wv = c >> 3, tt = c & 7;  // window-in-row, token-col
  float* rec = Bw + (((size_t)(b * 1024 + h1 * 32 + wv) * C3) + gc) * 64 + tt;

  float x0 = t[0][c], x1 = t[0][c + 1], x2 = t[0][c + 2];
  float y0 = t[1][c], y1 = t[1][c + 1], y2 = t[1][c + 2];
#pragma unroll
  for (int rr = 1; rr <= 8; ++rr) {
    const float z0 = t[rr + 1][c], z1 = t[rr + 1][c + 1], z2 = t[rr + 1][c + 2];
    const float res = x0 * w0 + x1 * w1 + x2 * w2
                    + y0 * w3 + y1 * w4 + y2 * w5
                    + z0 * w6 + z1 * w7 + z2 * w8;
    rec[(rr - 1) * 8] = res;
    x0 = y0; x1 = y1; x2 = y2;
    y0 = z0; y1 = z1; y2 = z2;
  }
}

// ---------------------------------------------------------------------------
// K2b: windowed channel attention + mlp gate from windowed dw-qkv.
// One block per (win, head, b). Fully-contiguous float4 global reads.
// LDS stride 68 (16B-aligned rows, conflict-free/2-way patterns).
// ---------------------------------------------------------------------------
__global__ __launch_bounds__(256, 3) void attn_win(
    const float* __restrict__ Bw, const float* __restrict__ temp,
    const float* __restrict__ mlpw, const float* __restrict__ mlpb,
    float* __restrict__ yw) {
  __shared__ float dwv[96 * 68];   // [gc][t]: q 0..31, k 32..63, v 64..95
  __shared__ float mwT[64 * 68];   // [x][y] transposed mlp weights
  __shared__ float attnS[32 * 33];
  __shared__ float scl[64];
  const int head = blockIdx.x % 6;
  const int win  = blockIdx.x / 6;
  const int b    = blockIdx.y;
  const int tid = threadIdx.x;
  const int c8 = tid >> 3, t8 = (tid & 7) * 8;

  const float* rec = Bw + (size_t)(b * 1024 + win) * C3 * 64;
#pragma unroll
  for (int g = 0; g < 3; ++g) {
    const float* s = rec + (g * 192 + head * 32) * 64;
    const float4 v0 = *(const float4*)(s + tid * 8);
    const float4 v1 = *(const float4*)(s + tid * 8 + 4);
    float* d = &dwv[(g * 32 + c8) * 68 + t8];
    *(float4*)d = v0;
    *(float4*)(d + 4) = v1;
  }
  for (int e = tid; e < 4096; e += 256)
    mwT[(e & 63) * 68 + (e >> 6)] = mlpw[e];
  __syncthreads();

  if (tid < 64) {
    float ss = 0.f;
    const float* r = &dwv[tid * 68];
    for (int tt = 0; tt < 64; tt += 4) {
      const float4 v = *(const float4*)(r + tt);
      ss += v.x * v.x + v.y * v.y + v.z * v.z + v.w * v.w;
    }
    scl[tid] = 1.f / fmaxf(sqrtf(ss), 1e-12f);
  }
  __syncthreads();

  // logits + softmax
  {
    const int c = tid >> 3, m = tid & 7;
    float sa[4] = {0.f, 0.f, 0.f, 0.f};
    const float* qr = &dwv[c * 68];
    const float* k0 = &dwv[(32 + m * 4) * 68];
    for (int tt = 0; tt < 64; tt += 4) {
      const float4 q = *(const float4*)(qr + tt);
      const float4 ka = *(const float4*)(k0 + tt);
      const float4 kb = *(const float4*)(k0 + 68 + tt);
      const float4 kc = *(const float4*)(k0 + 136 + tt);
      const float4 kd = *(const float4*)(k0 + 204 + tt);
      sa[0] += q.x * ka.x + q.y * ka.y + q.z * ka.z + q.w * ka.w;
      sa[1] += q.x * kb.x + q.y * kb.y + q.z * kb.z + q.w * kb.w;
      sa[2] += q.x * kc.x + q.y * kc.y + q.z * kc.z + q.w * kc.w;
      sa[3] += q.x * kd.x + q.y * kd.y + q.z * kd.z + q.w * kd.w;
    }
    const float qs = scl[c] * temp[head];
#pragma unroll
    for (int j = 0; j < 4; ++j) sa[j] *= qs * scl[32 + m * 4 + j];
    float mx = fmaxf(fmaxf(sa[0], sa[1]), fmaxf(sa[2], sa[3]));
    for (int off = 1; off < 8; off <<= 1) mx = fmaxf(mx, __shfl_xor(mx, off, 8));
    float sum = 0.f;
#pragma unroll
    for (int j = 0; j < 4; ++j) {
      sa[j] = expf(sa[j] - mx);
      sum += sa[j];
    }
    for (int off = 1; off < 8; off <<= 1) sum += __shfl_xor(sum, off, 8);
    const float inv = 1.f / sum;
#pragma unroll
    for (int j = 0; j < 4; ++j) attnS[c * 33 + m * 4 + j] = sa[j] * inv;
  }
  __syncthreads();

  // out = attn@v ; gate = GELU(v@mlp^T + b) ; y = out*gate
  {
    const int c = tid >> 3, iy = tid & 7;
    float ov[8] = {0.f, 0.f, 0.f, 0.f, 0.f, 0.f, 0.f, 0.f};
    const float* vb = &dwv[64 * 68 + iy * 8];
    const float* as = &attnS[c * 33];
    for (int d = 0; d < 32; ++d) {
      const float a = as[d];
      const float4 x0 = *(const float4*)(vb + d * 68);
      const float4 x1 = *(const float4*)(vb + d * 68 + 4);
      ov[0] += a * x0.x; ov[1] += a * x0.y; ov[2] += a * x0.z; ov[3] += a * x0.w;
      ov[4] += a * x1.x; ov[5] += a * x1.y; ov[6] += a * x1.z; ov[7] += a * x1.w;
    }
    float gt[8];
#pragma unroll
    for (int j = 0; j < 8; ++j) gt[j] = mlpb[iy * 8 + j];
    const float* vc = &dwv[(64 + c) * 68];
    for (int x = 0; x < 64; ++x) {
      const float vv = vc[x];
      const float* mr = &mwT[x * 68 + iy * 8];
      const float4 m0 = *(const float4*)mr;
      const float4 m1 = *(const float4*)(mr + 4);
      gt[0] += vv * m0.x; gt[1] += vv * m0.y; gt[2] += vv * m0.z; gt[3] += vv * m0.w;
      gt[4] += vv * m1.x; gt[5] += vv * m1.y; gt[6] += vv * m1.z; gt[7] += vv * m1.w;
    }
    float res[8];
#pragma unroll
    for (int j = 0; j < 8; ++j) {
      const float gg = gt[j];
      res[j] = ov[j] * (0.5f * gg * (1.f + erff(gg * 0.70710678118654752f)));
    }
    float* dst = yw + (((size_t)(b * 1024 + win) * 192 + head * 32 + c) * 64
                       + iy * 8);
    *(float4*)dst       = make_float4(res[0], res[1], res[2], res[3]);
    *(float4*)(dst + 4) = make_float4(res[4], res[5], res[6], res[7]);
  }
}

// ---------------------------------------------------------------------------
// Fallback (round-2): fused dwconv + attention reading spatial qkv.
// Used only if ws_size < 604 MB.
// ---------------------------------------------------------------------------
__global__ __launch_bounds__(256, 3) void attn_fused(
    const float* __restrict__ qkv, const float* __restrict__ wdw,
    const float* __restrict__ temp, const float* __restrict__ mlpw,
    const float* __restrict__ mlpb, float* __restrict__ yw) {
  __shared__ float smA[4160];
  __shared__ float dwv[64 * 97];
  __shared__ float attnS[32 * 33];
  __shared__ float scl[64];
  const int bid = blockIdx.x;
  const int b   = bid / 6144;
  const int rr  = bid % 6144;
  const int xcd = rr & 7;
  const int s   = rr >> 3;
  const int head = s % 6;
  const int wloc = s / 6;
  const int win  = xcd * 128 + wloc;
  const int h1 = win >> 5, w1 = win & 31;
  const int tid = threadIdx.x;
  const int ch = tid >> 3;
  const int iy = tid & 7;

  const int row0 = h1 * 8 - 1, col0 = w1 * 8 - 1;
  for (int g = 0; g < 3; ++g) {
    __syncthreads();
    const size_t cbase = (size_t)b * C3 + g * 192 + head * 32;
    for (int idx = tid; idx < 3200; idx += 256) {
      const int c = idx / 100, rem = idx - c * 100;
      const int yy = rem / 10, xx = rem - yy * 10;
      const int gy = row0 + yy, gx = col0 + xx;
      float v = 0.f;
      if ((unsigned)gy < 256u && (unsigned)gx < 256u)
        v = qkv[((cbase + c) * 256 + gy) * 256 + gx];
      smA[c * 101 + rem] = v;
    }
    __syncthreads();
    const float* w9 = wdw + (size_t)(g * 192 + head * 32 + ch) * 9;
    const float w0 = w9[0], w1_ = w9[1], w2 = w9[2];
    const float w3 = w9[3], w4 = w9[4], w5 = w9[5];
    const float w6 = w9[6], w7 = w9[7], w8 = w9[8];
    const int gc = g * 32 + ch;
    const float* t0 = &smA[ch * 101 + iy * 10];
#pragma unroll
    for (int ix = 0; ix < 8; ++ix) {
      const float sv = t0[ix] * w0 + t0[ix + 1] * w1_ + t0[ix + 2] * w2
                     + t0[10 + ix] * w3 + t0[11 + ix] * w4 + t0[12 + ix] * w5
                     + t0[20 + ix] * w6 + t0[21 + ix] * w7 + t0[22 + ix] * w8;
      dwv[(iy * 8 + ix) * 97 + gc] = sv;
    }
  }
  __syncthreads();

  for (int e = tid; e < 4096; e += 256)
    smA[(e >> 6) * 65 + (e & 63)] = mlpw[e];
  if (tid < 64) {
    float ss = 0.f;
    for (int t = 0; t < 64; ++t) {
      const float v = dwv[t * 97 + tid];
      ss += v * v;
    }
    scl[tid] = 1.f / fmaxf(sqrtf(ss), 1e-12f);
  }
  __syncthreads();

  {
    const int c = tid >> 3, m = tid & 7;
    float sa[4] = {0.f, 0.f, 0.f, 0.f};
    for (int t = 0; t < 64; ++t) {
      const float qv = dwv[t * 97 + c];
#pragma unroll
      for (int j = 0; j < 4; ++j) sa[j] += qv * dwv[t * 97 + 32 + m * 4 + j];
    }
    const float qs = scl[c] * temp[head];
#pragma unroll
    for (int j = 0; j < 4; ++j) sa[j] *= qs * scl[32 + m * 4 + j];
    float mx = fmaxf(fmaxf(sa[0], sa[1]), fmaxf(sa[2], sa[3]));
    for (int off = 1; off < 8; off <<= 1) mx = fmaxf(mx, __shfl_xor(mx, off, 8));
    float sum = 0.f;
#pragma unroll
    for (int j = 0; j < 4; ++j) {
      sa[j] = expf(sa[j] - mx);
      sum += sa[j];
    }
    for (int off = 1; off < 8; off <<= 1) sum += __shfl_xor(sum, off, 8);
    const float inv = 1.f / sum;
#pragma unroll
    for (int j = 0; j < 4; ++j) attnS[c * 33 + m * 4 + j] = sa[j] * inv;
  }
  __syncthreads();

  {
    const int c = ch;
    float ov[8] = {0.f, 0.f, 0.f, 0.f, 0.f, 0.f, 0.f, 0.f};
    const int tb = iy * 8 * 97 + 64;
    for (int d = 0; d < 32; ++d) {
      const float a = attnS[c * 33 + d];
#pragma unroll
      for (int j = 0; j < 8; ++j) ov[j] += a * dwv[tb + j * 97 + d];
    }
    float gt[8];
#pragma unroll
    for (int j = 0; j < 8; ++j) gt[j] = mlpb[iy * 8 + j];
    for (int x = 0; x < 64; ++x) {
      const float vv = dwv[x * 97 + 64 + c];
#pragma unroll
      for (int j = 0; j < 8; ++j) gt[j] += vv * smA[(iy * 8 + j) * 65 + x];
    }
    float res[8];
#pragma unroll
    for (int j = 0; j < 8; ++j) {
      const float gg = gt[j];
      res[j] = ov[j] * (0.5f * gg * (1.f + erff(gg * 0.70710678118654752f)));
    }
    float* dst = yw + (((size_t)(b * 1024 + win) * 192 + head * 32 + c) * 64
                       + iy * 8);
    *(float4*)dst       = make_float4(res[0], res[1], res[2], res[3]);
    *(float4*)(dst + 4) = make_float4(res[4], res[5], res[6], res[7]);
  }
}

// ---------------------------------------------------------------------------
// K3: proj GEMM reading windowed yw, writing spatial out (+bias).
// ---------------------------------------------------------------------------
__global__ __launch_bounds__(256) void proj_gemm(
    const float* __restrict__ yw, const float* __restrict__ Wm,
    const float* __restrict__ bias, float* __restrict__ out) {
  __shared__ float As[16][68];
  __shared__ float Bs[16][256];
  const int ptile = blockIdx.x;
  const int ot = blockIdx.y * 64;
  const int b  = blockIdx.z;
  const int h1 = ptile >> 3, w4 = ptile & 7;
  const int win0 = h1 * 32 + w4 * 4;
  const int tid = threadIdx.x;
  const int tx = tid & 15, ty = tid >> 4;
  const int oA = tid >> 2, kA = (tid & 3) * 4;
  float acc[4][16];
#pragma unroll
  for (int i = 0; i < 4; ++i)
#pragma unroll
    for (int j = 0; j < 16; ++j) acc[i][j] = 0.f;

  const float* ywb = yw + (size_t)(b * 1024 + win0) * 192 * 64;
  for (int k0 = 0; k0 < 192; k0 += 16) {
    float4 av = *(const float4*)(Wm + (size_t)(ot + oA) * 192 + k0 + kA);
    As[kA + 0][oA] = av.x;
    As[kA + 1][oA] = av.y;
    As[kA + 2][oA] = av.z;
    As[kA + 3][oA] = av.w;
#pragma unroll
    for (int i = 0; i < 4; ++i) {
      const int f4 = tid + 256 * i;
      const int k = f4 >> 6, p4 = f4 & 63;
      const int wv = p4 >> 4, tt = (p4 & 15) * 4;
      *(float4*)&Bs[k][p4 * 4] =
          *(const float4*)(ywb + ((size_t)wv * 192 + k0 + k) * 64 + tt);
    }
    __syncthreads();
#pragma unroll
    for (int k = 0; k < 16; ++k) {
      const float a0 = As[k][ty * 4 + 0];
      const float a1 = As[k][ty * 4 + 1];
      const float a2 = As[k][ty * 4 + 2];
      const float a3 = As[k][ty * 4 + 3];
#pragma unroll
      for (int j = 0; j < 16; ++j) {
        const float bv = Bs[k][tx + 16 * j];
        acc[0][j] += a0 * bv;
        acc[1][j] += a1 * bv;
        acc[2][j] += a2 * bv;
        acc[3][j] += a3 * bv;
      }
    }
    __syncthreads();
  }
  const int colbase = w4 * 32;
#pragma unroll
  for (int i = 0; i < 4; ++i) {
    const int o = ot + ty * 4 + i;
    const float bv = bias[o];
    float* ob = out + ((size_t)(b * 192 + o) * 256 + h1 * 8) * 256 + colbase;
#pragma unroll
    for (int j = 0; j < 16; ++j) {
      const int p = tx + 16 * j;
      const int wv = p >> 6;
      const int t = p & 63;
      ob[(t >> 3) * 256 + wv * 8 + (t & 7)] = acc[i][j] + bv;
    }
  }
}

extern "C" void kernel_launch(void* const* d_in, const int* in_sizes, int n_in,
                              void* d_out, int out_size, void* d_ws, size_t ws_size,
                              hipStream_t stream) {
  const float* x           = (const float*)d_in[0];
  const float* w_qkv       = (const float*)d_in[1];
  const float* w_dw        = (const float*)d_in[2];
  const float* temperature = (const float*)d_in[3];
  const float* mlp_w       = (const float*)d_in[4];
  const float* mlp_b       = (const float*)d_in[5];
  const float* proj_w      = (const float*)d_in[6];
  const float* proj_b      = (const float*)d_in[7];
  float* out = (float*)d_out;

  const size_t szA = (size_t)2 * C3 * HWSZ;  // elements: spatial qkv / windowed buf
  float* ws0 = (float*)d_ws;

  if (ws_size >= 2 * szA * sizeof(float)) {
    // New path: spatial qkv in A, dw-windowed in B, yw reuses A.
    float* Bw = ws0 + szA;
    float* yw = ws0;
    conv1x1_gemm<<<dim3(1024, 9, 2), 256, 0, stream>>>(x, w_qkv, ws0);
    dwconv_win<<<dim3(C3, 32, 2), 256, 0, stream>>>(ws0, w_dw, Bw);
    attn_win<<<dim3(6144, 2), 256, 0, stream>>>(Bw, temperature, mlp_w, mlp_b, yw);
    proj_gemm<<<dim3(256, 3, 2), 256, 0, stream>>>(yw, proj_w, proj_b, out);
  } else {
    // Fallback (round-2 footprint: 402 MB).
    float* yw = ws0 + szA;
    conv1x1_gemm<<<dim3(1024, 9, 2), 256, 0, stream>>>(x, w_qkv, ws0);
    attn_fused<<<dim3(12288), 256, 0, stream>>>(ws0, w_dw, temperature,
                                                mlp_w, mlp_b, yw);
    proj_gemm<<<dim3(256, 3, 2), 256, 0, stream>>>(yw, proj_w, proj_b, out);
  }
}